// Round 11
// baseline (75.739 us; speedup 1.0000x reference)
//
#include <hip/hip_runtime.h>

// Problem constants (fixed by setup_inputs)
#define T_DIM 32
#define B_DIM 64
#define D_DIM 256
#define P_DIM 1024
#define NK    17
#define DT    0.1875f    // 3/16
#define DT_REV 0.029841551329651566f   // DT / (2*pi) -- v_sin/v_cos take revolutions

#define LROW  264        // padded bf16 row (256+8): 132 dw = 4 mod 32 -> 2-way (free)

typedef __bf16 bf16x8 __attribute__((ext_vector_type(8)));
typedef float  f32x4  __attribute__((ext_vector_type(4)));

// Native bf16 pack: lowers to v_cvt_pk_bf16_f32 (RNE).
static __device__ __forceinline__ unsigned pkbf(float lo, float hi) {
  unsigned short a = __builtin_bit_cast(unsigned short, (__bf16)lo);
  unsigned short b = __builtin_bit_cast(unsigned short, (__bf16)hi);
  return (unsigned)a | ((unsigned)b << 16);
}

// Opaque zero derived from x: forces the wave to wait for x (s_waitcnt) and
// gives the compiler an unfoldable data dependency.
static __device__ __forceinline__ int dep_zero(float x) {
  int d;
  asm volatile("v_and_b32 %0, 0, %1" : "=v"(d) : "v"(x));
  return d;
}

// Module-scope scratch (load-time zero-init; NOT poisoned by the harness).
// ALL accesses RELAXED device-scope atomics (R4/R5: ordered agent-scope ops
// poison L2 on non-coherent XCDs). Flat structure (R6-R10 proven).
// Counter never reset; last-arrival test (old & 1023)==1023 is wrap-safe.
__device__ float g_sum[64 * 32];
__device__ int   g_counter = 0;

// ---------------------------------------------------------------------------
// OCCUPANCY REDESIGN: 16x16x32 MFMA quarters the per-wave tile -> 8192 waves
// (24 resident/CU at 3 blocks/CU, vs R8's 8) so load/barrier latency is
// finally hidden. grid (32 ptile, 32 t) x 512 thr (8 waves = 4 bt x 2 pt).
//  - proj staged ONCE per block (shared by 8 waves -> proj L2 traffic same
//    as R8): [64 b][264 k] bf16, no transpose (rows k-contiguous).
//  - A staged [32 p][264 k] bf16 transposed; column sq-norms via in-wave
//    shfl_xor reduce -> normred[8][32] -> invn[32] (norm applied after GEMM).
//  - per wave: 8 x mfma_f32_16x16x32_bf16, acc 4 regs.
//    C/D: col=lane&15, row=(lane>>4)*4+reg (HW-verified m89/m91).
//    A/B frags: row/col=lane&15, k=ks*32+(lane>>4)*8+j (k-grouped, as in the
//    session's verified 32x32 usage).
//  - trig: 4 elements/lane, same Chebyshev; combine b-rows via shfl_xor
//    16/32; cross-wave combine over 4 b-tiles via small LDS exch (aliases
//    dead proj tile); waves bt=0 compute the 16-harmonic error in-register.
//  - tail: R9/R10 flat relaxed atomic protocol verbatim (mask 1023).
// LDS: sp 33792 B | sa 16896 B | normred 1 KB | invn 128 B | parts 8 B
//   = 51848 B -> 3 blocks/CU. exch (12.7 KB) aliases sp post-barrier (2).
// ---------------------------------------------------------------------------
__global__ __launch_bounds__(512, 6) void sig_fused_kernel(const float* __restrict__ proj,
                                                           const float* __restrict__ A,
                                                           float* __restrict__ out) {
  __shared__ float smf[12962];
  unsigned short* sp = (unsigned short*)smf;           // proj [64][264] bf16
  unsigned short* sa = (unsigned short*)(smf + 8448);  // A^T  [32][264] bf16
  float* normred = smf + 12672;                        // [8 wv][32 p]
  float* invn    = smf + 12928;                        // [32]
  float* parts   = smf + 12960;                        // [2]
  float* exch    = smf;                                // aliases sp post-(2)

  const int tid  = threadIdx.x;
  const int lane = tid & 63;
  const int wv   = tid >> 6;                     // 0..7
  const int p0   = blockIdx.x * 32;
  const int t    = blockIdx.y;
  const int bt   = wv >> 1;                      // b-16-tile 0..3
  const int pt   = wv & 1;                       // p-16-tile 0..1
  const int l15  = lane & 15;
  const int kg4  = lane >> 4;                    // k-group 0..3

  // ---- stage proj: thread owns row b = tid>>3, 128 B k-segment ----
  {
    const int b  = tid >> 3;                     // 0..63
    const int c4 = (tid & 7) * 8;                // float4 index in row
    const float4* Pg = (const float4*)(proj + (size_t)t * B_DIM * D_DIM);
    float4 u[8];
#pragma unroll
    for (int i = 0; i < 8; ++i) u[i] = Pg[b * 64 + c4 + i];
    unsigned short* dst = &sp[b * LROW + (tid & 7) * 32];
#pragma unroll
    for (int i = 0; i < 4; ++i) {
      uint4 w;
      w.x = pkbf(u[2 * i].x,     u[2 * i].y);
      w.y = pkbf(u[2 * i].z,     u[2 * i].w);
      w.z = pkbf(u[2 * i + 1].x, u[2 * i + 1].y);
      w.w = pkbf(u[2 * i + 1].z, u[2 * i + 1].w);
      *(uint4*)&dst[i * 8] = w;
    }
  }

  // ---- stage A: thread owns 4 p-cols (pg) x 4 k's (kg); norms in-wave ----
  {
    const int pg = tid & 7;                      // p-quad
    const int kg = tid >> 3;                     // 0..63 (wave covers 8)
    const float4* Ag = (const float4*)(A + p0); // row stride P_DIM/4 float4
    float4 va[4];
#pragma unroll
    for (int i = 0; i < 4; ++i)
      va[i] = Ag[(size_t)(kg * 4 + i) * (P_DIM / 4) + pg];
    float nrm[4];
#pragma unroll
    for (int j = 0; j < 4; ++j) {
      float e0 = ((const float*)&va[0])[j], e1 = ((const float*)&va[1])[j];
      float e2 = ((const float*)&va[2])[j], e3 = ((const float*)&va[3])[j];
      float n = e0 * e0;
      n = fmaf(e1, e1, n); n = fmaf(e2, e2, n); n = fmaf(e3, e3, n);
      nrm[j] = n;
      uint2 w;
      w.x = pkbf(e0, e1);
      w.y = pkbf(e2, e3);
      *(uint2*)&sa[(pg * 4 + j) * LROW + kg * 4] = w;
    }
    // reduce over the wave's 8 kg-groups (lane bits 3..5) -> per-p partial
#pragma unroll
    for (int j = 0; j < 4; ++j) {
      nrm[j] += __shfl_xor(nrm[j], 8, 64);
      nrm[j] += __shfl_xor(nrm[j], 16, 64);
      nrm[j] += __shfl_xor(nrm[j], 32, 64);
    }
    if (lane < 8) {
#pragma unroll
      for (int j = 0; j < 4; ++j) normred[wv * 32 + pg * 4 + j] = nrm[j];
    }
  }
  __syncthreads();                               // (1) tiles + normred ready

  // ---- finish column norms -> invn[p] (overlaps other waves' MFMA) ----
  if (tid < 32) {
    float s = 0.f;
#pragma unroll
    for (int q = 0; q < 8; ++q) s += normred[q * 32 + tid];
    invn[tid] = rsqrtf(fmaxf(s, 1e-24f));        // 1/clamp_min(norm, 1e-12)
  }

  // ---- MFMA: 8 k-steps of K=32 ----
  f32x4 acc = {0.f, 0.f, 0.f, 0.f};
  const unsigned short* arow = &sp[(bt * 16 + l15) * LROW + kg4 * 8];
  const unsigned short* brow = &sa[(pt * 16 + l15) * LROW + kg4 * 8];
#pragma unroll
  for (int ks = 0; ks < 8; ++ks) {
    bf16x8 afr = *(const bf16x8*)(arow + ks * 32);
    bf16x8 bfr = *(const bf16x8*)(brow + ks * 32);
    acc = __builtin_amdgcn_mfma_f32_16x16x32_bf16(afr, bfr, acc, 0, 0, 0);
  }
  // acc[r] = x_unnorm[b = bt*16 + (lane>>4)*4 + r][p = p0 + pt*16 + l15]
  __syncthreads();                               // (2) invn ready; sp/sa dead

  // scale to REVOLUTIONS: theta = x*DT, hw trig wants theta/2pi
  const float invdt = invn[pt * 16 + l15] * DT_REV;

  // ---- Chebyshev trig via HW v_sin/v_cos: sums over this lane's 4 b's ----
  float cs[NK - 1], ss[NK - 1];
#pragma unroll
  for (int k = 0; k < NK - 1; ++k) { cs[k] = 0.f; ss[k] = 0.f; }
#pragma unroll
  for (int r = 0; r < 4; ++r) {
    float th = acc[r] * invdt;                   // revolutions, |th| << 1
    float c1 = __builtin_amdgcn_cosf(th);        // v_cos_f32: cos(2*pi*th)
    float s1 = __builtin_amdgcn_sinf(th);        // v_sin_f32: sin(2*pi*th)
    float twoc = 2.f * c1;
    float ckm1 = 1.f, skm1 = 0.f;
    float ck = c1, sk = s1;
    cs[0] += c1;
    ss[0] += s1;
#pragma unroll
    for (int k = 2; k < NK; ++k) {
      float cn = fmaf(twoc, ck, -ckm1);
      float sn = fmaf(twoc, sk, -skm1);
      cs[k - 1] += cn;
      ss[k - 1] += sn;
      ckm1 = ck; skm1 = sk; ck = cn; sk = sn;
    }
  }

  // ---- combine the 4 lane-row-groups (lanes l, l^16, l^32, l^48 share p) --
#pragma unroll
  for (int k = 0; k < NK - 1; ++k) {
    cs[k] += __shfl_xor(cs[k], 16, 64);
    cs[k] += __shfl_xor(cs[k], 32, 64);
    ss[k] += __shfl_xor(ss[k], 16, 64);
    ss[k] += __shfl_xor(ss[k], 32, 64);
  }
  // every lane: this wave's full 16-b sums for p-col = p0 + pt*16 + l15

  // ---- waves bt>0 export to exch (aliases dead sp; 33-f pad) ----
  if (bt > 0 && lane < 16) {
    float* row = &exch[((bt - 1) * 2 + pt) * 528 + l15 * 33];
#pragma unroll
    for (int k = 0; k < NK - 1; ++k) {
      row[k]      = cs[k];
      row[16 + k] = ss[k];
    }
  }
  __syncthreads();                               // (3) exch ready

  // ---- waves bt=0: combine 4 b-tiles + all-16-harmonics error ----
  if (bt == 0) {
    const float* r0 = &exch[(0 * 2 + pt) * 528 + l15 * 33];
    const float* r1 = &exch[(1 * 2 + pt) * 528 + l15 * 33];
    const float* r2 = &exch[(2 * 2 + pt) * 528 + l15 * 33];
    float part = 0.f;
#pragma unroll
    for (int k = 0; k < NK - 1; ++k) {
      float C = cs[k] + r0[k] + r1[k] + r2[k];
      float S = ss[k] + r0[16 + k] + r1[16 + k] + r2[16 + k];
      float cm  = C * (1.f / 64.f);
      float sm_ = S * (1.f / 64.f);
      float tk  = (float)(k + 1) * DT;
      float phi = __expf(-0.5f * tk * tk);
      float wk  = ((k == NK - 2) ? DT : 2.f * DT) * phi;  // k=16 endpoint
      float dc  = cm - phi;
      part = fmaf(wk, fmaf(dc, dc, sm_ * sm_), part);
    }
    // 4x lane replication within the wave -> (1/512)/4
    part *= (1.f / 2048.f);
#pragma unroll
    for (int off = 32; off > 0; off >>= 1)
      part += __shfl_down(part, off, 64);
    if (lane == 0) parts[pt] = part;
  }
  __syncthreads();                               // (4) parts ready

  // ---- flat relaxed tail (R9/R10 proven): spread lines + one counter ----
  if (wv == 0) {
    const int bid = t * 32 + blockIdx.x;         // 0..1023
    int isl = 0;
    if (lane == 0) {
      float total = parts[0] + parts[1];
      float oldv = atomicAdd(&g_sum[(bid & 63) * 32], total);
      // dep_zero: sum-RMW provably performed before the counter bump issues
      int oc = atomicAdd(&g_counter, 1 + dep_zero(oldv));
      isl = ((oc & 1023) == 1023);               // wrap-safe across replays
    }
    isl = __shfl(isl, 0, 64);
    if (isl) {
      // All 1024 sum-RMWs performed (counter protocol). 64 parallel
      // exchanges gather + re-arm each line in one round trip.
      float s = atomicExch(&g_sum[lane * 32], 0.0f);
#pragma unroll
      for (int off = 32; off > 0; off >>= 1)
        s += __shfl_down(s, off, 64);
      if (lane == 0) out[0] = s;                 // overwrite poison
    }
  }
}

// ---------------------------------------------------------------------------
extern "C" void kernel_launch(void* const* d_in, const int* in_sizes, int n_in,
                              void* d_out, int out_size, void* d_ws, size_t ws_size,
                              hipStream_t stream) {
  const float* proj = (const float*)d_in[0];     // (32,64,256) fp32
  const float* A    = (const float*)d_in[1];     // (256,1024) fp32
  float* out        = (float*)d_out;             // 1 fp32 scalar

  // ONE dispatch: no memset -- the finishing block plain-stores the scalar.
  sig_fused_kernel<<<dim3(32, 32), dim3(512), 0, stream>>>(proj, A, out);
}